// Round 7
// baseline (323.340 us; speedup 1.0000x reference)
//
#include <hip/hip_runtime.h>

#define NROW 8192
#define NCOL 8192
#define RANK 256

#define BM 128
#define BN 128
#define BK 64
#define NKT (RANK / BK)   // 4 K-steps

typedef __bf16  bf16x8 __attribute__((ext_vector_type(8)));
typedef float   f32x4  __attribute__((ext_vector_type(4)));

__device__ __forceinline__ unsigned short f2bf(float f) {
    // round-to-nearest-even fp32 -> bf16
    unsigned int u = __builtin_bit_cast(unsigned int, f);
    u += 0x7fffu + ((u >> 16) & 1u);
    return (unsigned short)(u >> 16);
}

// --- Prologue A: X (fp32, NROW x RANK) -> Xb (bf16) + x2 row norms ---
__global__ __launch_bounds__(256) void prep_x(const float* __restrict__ X,
                                              unsigned short* __restrict__ Xb,
                                              float* __restrict__ x2) {
    const int row  = blockIdx.x * 4 + (threadIdx.x >> 6);
    const int lane = threadIdx.x & 63;
    const float4 v = ((const float4*)(X + (size_t)row * RANK))[lane];
    float s = v.x * v.x + v.y * v.y + v.z * v.z + v.w * v.w;
    ushort4 b;
    b.x = f2bf(v.x); b.y = f2bf(v.y); b.z = f2bf(v.z); b.w = f2bf(v.w);
    ((ushort4*)(Xb + (size_t)row * RANK))[lane] = b;
    #pragma unroll
    for (int off = 32; off > 0; off >>= 1) s += __shfl_down(s, off);
    if (lane == 0) x2[row] = s;
}

// --- Prologue B: Y (fp32, RANK x NCOL) -> Ybt (bf16, NCOL x RANK) + y2 ---
__global__ __launch_bounds__(256) void prep_y(const float* __restrict__ Y,
                                              unsigned short* __restrict__ Ybt,
                                              float* __restrict__ y2) {
    __shared__ float tile[64][65];   // +1 pad: conflict-free transposed reads
    __shared__ float part[256];
    const int t  = threadIdx.x;
    const int j0 = blockIdx.x * 64;
    const int tq = t >> 6;           // 0..3
    const int tl = t & 63;
    float acc = 0.f;
    for (int c = 0; c < 4; ++c) {    // k chunks of 64
        const int k0 = c * 64;
        #pragma unroll
        for (int i = 0; i < 16; ++i) {
            const int kk = tq * 16 + i;
            const float v = Y[(size_t)(k0 + kk) * NCOL + j0 + tl]; // coalesced
            tile[kk][tl] = v;
            acc += v * v;            // column j0+tl partial
        }
        __syncthreads();
        #pragma unroll
        for (int i = 0; i < 16; ++i) {
            const int jj = tq * 16 + i;
            Ybt[(size_t)(j0 + jj) * RANK + k0 + tl] = f2bf(tile[tl][jj]); // coalesced
        }
        __syncthreads();
    }
    part[t] = acc;
    __syncthreads();
    if (t < 64)
        y2[j0 + t] = part[t] + part[t + 64] + part[t + 128] + part[t + 192];
}

// --- Main: bf16 MFMA GEMM (R6 structure) + swizzled staging LDS ---
// R6 found: staging-tile fragment reads were a 16-WAY BANK CONFLICT
// ([row][64] bf16 = 128 B rows; lanes 0-15 read 16 rows at the same 16B
// slot -> one 4-bank group). Arithmetic: 64 reads/wave x 8 waves/CU x
// ~68 cyc = ~116 us chip-wide = the whole unexplained gap (m201 pathology).
//
// Fix (rule: both-sides-or-neither with global_load_lds): LDS dest stays
// LINEAR; per-lane GLOBAL source k-slot is pre-swizzled s^(row&7); fragment
// reads apply the same XOR. Post-swizzle each 16-lane group spreads over all
// 8 four-bank groups, 2 lanes/bank = free (m136).
//
// Epilogue (R6, kept): C-tile through LDS (swizzled), then linear full-line
// stores: 2 rows x 512 B contiguous per instruction.
//
// Operand-SWAPPED mfma: acc[mt][nt] elem r at lane L holds
//   C[row = rowBase+waveM+mt*16+(L&15)][col = colBase+waveN+nt*16+(L>>4)*4+r]
__global__ __launch_bounds__(256, 2)
void l2_gemm(const unsigned short* __restrict__ A,   // Xb  [NROW][RANK]
             const unsigned short* __restrict__ Bt,  // Ybt [NCOL][RANK]
             const float* __restrict__ x2,
             const float* __restrict__ y2,
             const float* __restrict__ beta_p,
             float* __restrict__ out) {
    // 64 KB union: staging buffers during K-loop, fp32 C-tile in epilogue
    __shared__ alignas(16) unsigned char smem[64 * 1024];
    auto As = (unsigned short (*)[BM * BK])(smem);            // [2][8192], 32 KB
    auto Bs = (unsigned short (*)[BN * BK])(smem + 32768);    // [2][8192], 32 KB
    float* Cs = (float*)smem;                                 // [128][128], 64 KB

    const int t    = threadIdx.x;
    const int wid  = t >> 6;
    const int lane = t & 63;
    const int rowBase = blockIdx.x * BM;
    const int colBase = blockIdx.y * BN;

    const int waveM = (wid >> 1) * 64;
    const int waveN = (wid & 1) * 64;

    f32x4 acc[4][4] = {};

    const int lrow = lane >> 3;                    // 0..7 : row within 8-row chunk
    const int lcolsw = (((lane & 7) ^ lrow)) * 8;  // PRE-SWIZZLED source k-slot

    // per-lane global source: row as before, k-column swizzled by row&7.
    // (row&7 == lrow because chunk bases are multiples of 8)
    const unsigned short* gA = A  + (size_t)(rowBase + wid * 8 + lrow) * RANK + lcolsw;
    const unsigned short* gB = Bt + (size_t)(colBase + wid * 8 + lrow) * RANK + lcolsw;

    auto stage = [&](int buf, int kt) {
        #pragma unroll
        for (int r = 0; r < 4; ++r) {
            const int rrel = r * 32 + wid * 8;   // wave-uniform LDS row base
            __builtin_amdgcn_global_load_lds(
                (__attribute__((address_space(1))) void*)(gA + (size_t)r * 32 * RANK + kt),
                (__attribute__((address_space(3))) void*)(&As[buf][rrel * BK]), 16, 0, 0);
            __builtin_amdgcn_global_load_lds(
                (__attribute__((address_space(1))) void*)(gB + (size_t)r * 32 * RANK + kt),
                (__attribute__((address_space(3))) void*)(&Bs[buf][rrel * BK]), 16, 0, 0);
        }
    };

    auto compute = [&](int buf) {
        #pragma unroll
        for (int ks = 0; ks < BK; ks += 32) {
            const int slbase = (ks >> 3) + (lane >> 4);   // logical 16B slot 0..7
            bf16x8 af[4], bfr[4];
            #pragma unroll
            for (int mt = 0; mt < 4; ++mt) {
                const int row = waveM + mt * 16 + (lane & 15);
                const int ps  = slbase ^ (row & 7);       // swizzled read slot
                af[mt] = *(const bf16x8*)(&As[buf][row * BK + ps * 8]);
            }
            #pragma unroll
            for (int nt = 0; nt < 4; ++nt) {
                const int row = waveN + nt * 16 + (lane & 15);
                const int ps  = slbase ^ (row & 7);
                bfr[nt] = *(const bf16x8*)(&Bs[buf][row * BK + ps * 8]);
            }
            #pragma unroll
            for (int mt = 0; mt < 4; ++mt)
                #pragma unroll
                for (int nt = 0; nt < 4; ++nt)
                    // SWAPPED operands: output mapping transposed (see header)
                    acc[mt][nt] = __builtin_amdgcn_mfma_f32_16x16x32_bf16(
                        bfr[nt], af[mt], acc[mt][nt], 0, 0, 0);
        }
    };

    // 2-phase pipeline: stage(k+1) issued before compute(k); one barrier/K-step.
    stage(0, 0);
    __syncthreads();
    #pragma unroll
    for (int kt = 1; kt < NKT; ++kt) {
        stage(kt & 1, kt * BK);            // prefetch next tile (in flight during MFMA)
        compute((kt - 1) & 1);
        __syncthreads();                   // drain prefetch + barrier
    }

    // epilogue operand prefetch: latency hides under the final compute
    const int r0 = rowBase + waveM + (lane & 15);
    const int c0 = colBase + waveN + ((lane >> 4) << 2);
    const float beta = *beta_p;
    float xv[4];
    f32x4 y4[4];
    #pragma unroll
    for (int mt = 0; mt < 4; ++mt) xv[mt] = x2[r0 + mt * 16];
    #pragma unroll
    for (int nt = 0; nt < 4; ++nt) y4[nt] = *(const f32x4*)(y2 + c0 + nt * 16);

    compute((NKT - 1) & 1);
    __syncthreads();   // all waves done reading As/Bs before Cs overwrites them

    // ---- phase 1: compute z, write to swizzled LDS C-tile ----
    #pragma unroll
    for (int mt = 0; mt < 4; ++mt) {
        const int trow = waveM + mt * 16 + (lane & 15);
        #pragma unroll
        for (int nt = 0; nt < 4; ++nt) {
            const f32x4 a = acc[mt][nt];
            f32x4 z;
            #pragma unroll
            for (int r = 0; r < 4; ++r) {
                float d2 = xv[mt] + y4[nt][r] - 2.0f * a[r];
                z[r] = beta - __builtin_amdgcn_sqrtf(fmaxf(d2, 0.0f));
            }
            const int slot = ((waveN >> 2) + nt * 4 + (lane >> 4)) ^ (trow & 7);
            *(f32x4*)(&Cs[trow * 128 + slot * 4]) = z;   // <=2-way bank conflict
        }
    }
    __syncthreads();

    // ---- phase 2: linear full-line stores; 2 rows x 512 B per instruction ----
    {
        const int l5 = lane >> 5;
        const int g  = lane & 31;
        #pragma unroll
        for (int i = 0; i < 16; ++i) {
            const int trow = wid * 32 + i * 2 + l5;
            const int slot = g ^ (trow & 7);             // un-swizzle
            const f32x4 v = *(const f32x4*)(&Cs[trow * 128 + slot * 4]);
            *(f32x4*)(out + (size_t)(rowBase + trow) * NCOL + colBase + g * 4) = v;
        }
    }
}

extern "C" void kernel_launch(void* const* d_in, const int* in_sizes, int n_in,
                              void* d_out, int out_size, void* d_ws, size_t ws_size,
                              hipStream_t stream) {
    const float* X    = (const float*)d_in[0];   // 8192 x 256
    const float* Y    = (const float*)d_in[1];   // 256 x 8192
    const float* beta = (const float*)d_in[2];   // scalar
    float* out = (float*)d_out;

    // workspace layout
    char* ws = (char*)d_ws;
    unsigned short* Xb  = (unsigned short*)(ws);                           // 4 MB
    unsigned short* Ybt = (unsigned short*)(ws + (size_t)4 * 1024 * 1024); // 4 MB
    float* x2 = (float*)(ws + (size_t)8 * 1024 * 1024);                    // 32 KB
    float* y2 = (float*)(ws + (size_t)8 * 1024 * 1024 + 32 * 1024);        // 32 KB

    prep_x<<<NROW / 4, 256, 0, stream>>>(X, Xb, x2);
    prep_y<<<NCOL / 64, 256, 0, stream>>>(Y, Ybt, y2);

    dim3 grid(NROW / BM, NCOL / BN);
    l2_gemm<<<grid, 256, 0, stream>>>(Xb, Ybt, x2, y2, beta, out);
}